// Round 6
// baseline (132.294 us; speedup 1.0000x reference)
//
#include <hip/hip_runtime.h>
#include <hip/hip_fp16.h>
#include <math.h>

#define B_  2
#define CIN 64
#define COUT 64
#define H_  192
#define W_  192
#define G_  2
#define KK_ 9
#define CG_ 32
#define HW_ (H_*W_)
#define PIX 32            // pixels per block (x-contiguous)
#define XT_ (W_/PIX)      // 6 x-tiles per row
#define PR_ 7             // patch rows (y-3 .. y+3)
#define PC_ 38            // patch cols (x0-3 .. x0+34)
#define PST 72            // patch row stride in shorts (64 ch + 8 pad)
#define DSTR 69           // dout row stride in floats (bank-spread)
#define RST 38            // redh row stride in shorts (conflict-free: 19 odd)
#define NB_NHWC (B_ * (HW_ / 64))        // 1152
#define NB_WT   ((18*4*64*8 + 18*2*64*8) / 256)   // 216
#define NB_RO   (B_ * HW_ / 256)         // 288 region-offset precompute blocks

typedef __attribute__((ext_vector_type(8))) short bf16x8;      // 8x16-bit container
typedef __attribute__((ext_vector_type(8))) _Float16 f16x8;
typedef __attribute__((ext_vector_type(4))) unsigned int u32x4;
typedef __attribute__((ext_vector_type(4))) float f32x4;

static __device__ __forceinline__ short f2h(float f) {
    _Float16 h = (_Float16)f;
    return __builtin_bit_cast(short, h);
}
static __device__ __forceinline__ float h2f(short s) {
    _Float16 h = __builtin_bit_cast(_Float16, s);
    return (float)h;
}
static __device__ __forceinline__ unsigned pk2hu(float lo, float hi) {
    auto h = __builtin_amdgcn_cvt_pkrtz(lo, hi);   // __fp16 ext_vector(2)
    return __builtin_bit_cast(unsigned, h);
}
static __device__ __forceinline__ short2 pk2h(float lo, float hi) {
    auto h = __builtin_amdgcn_cvt_pkrtz(lo, hi);
    return __builtin_bit_cast(short2, h);
}
static __device__ __forceinline__ __half2 bcl(unsigned u) {      // broadcast low half
    return __builtin_bit_cast(__half2, (unsigned)((u & 0xffffu) | (u << 16)));
}
static __device__ __forceinline__ __half2 bch(unsigned u) {      // broadcast high half
    return __builtin_bit_cast(__half2, (unsigned)((u >> 16) | (u & 0xffff0000u)));
}
static __device__ __forceinline__ __half2 H2(unsigned u) {
    return __builtin_bit_cast(__half2, u);
}
// extract fp16 element j (0..7) of a 16B quad as float (j compile-time)
static __device__ __forceinline__ float hx(u32x4 q, int j) {
    unsigned u = q[j >> 1];
    return h2f((short)((j & 1) ? (u >> 16) : (u & 0xffffu)));
}

// ---------------------------------------------------------------------------
// Kernel A: prep — NCHW->NHWC fp16 transform + weight pack + region-offset
// precompute (off[18], sigmoid(m1)[9] per pixel, fp16, 32-short record).
// ---------------------------------------------------------------------------
__global__ __launch_bounds__(256)
void prep_kernel(const float* __restrict__ in,
                 const float* __restrict__ weight,
                 const float* __restrict__ sem_w,
                 const float* __restrict__ m2_w,
                 const float* __restrict__ mask_in,
                 const float* __restrict__ reg_w, const float* __restrict__ reg_b,
                 const float* __restrict__ m1_w, const float* __restrict__ m1_b,
                 short* __restrict__ inpT,
                 short* __restrict__ wbm,
                 short* __restrict__ wbs,
                 short* __restrict__ roff) {
    __shared__ float t[64][65];
    const int tid = threadIdx.x;
    const int bid = blockIdx.x;
    if (bid < NB_NHWC) {
        const int b = bid / (HW_ / 64);
        const int pix0 = (bid % (HW_ / 64)) * 64;
        const float* src = in + (size_t)b * CIN * HW_ + pix0;
        const int c0 = (tid >> 6) * 16;
        const int p  = tid & 63;
        #pragma unroll
        for (int i = 0; i < 16; ++i)
            t[c0 + i][p] = src[(size_t)(c0 + i) * HW_ + p];
        __syncthreads();
        short* dst = inpT + ((size_t)b * HW_ + pix0) * 64;
        #pragma unroll
        for (int i = 0; i < 2; ++i) {
            int item = i * 256 + tid;
            int pp = item >> 3, oct = item & 7;
            bf16x8 v;
            #pragma unroll
            for (int j = 0; j < 8; j += 2) {
                short2 ss = pk2h(t[oct * 8 + j][pp], t[oct * 8 + j + 1][pp]);
                v[j] = ss.x; v[j + 1] = ss.y;
            }
            *(bf16x8*)&dst[pp * 64 + oct * 8] = v;
        }
        return;
    }
    if (bid >= NB_NHWC + NB_WT) {
        // ---- region offsets + m1 sigmoid from mask_in (mask-only inputs) ----
        const int pix = (bid - NB_NHWC - NB_WT) * 256 + tid;   // < B*HW
        const int b = pix / HW_;
        const int p = pix - b * HW_;
        const int yy = p / W_;
        const int xx = p - yy * W_;
        const float* mbp = mask_in + (size_t)b * HW_ + p;
        const bool vxm = xx > 0, vxp = (xx + 1) < W_;
        const bool vym = yy > 0, vyp = (yy + 1) < H_;
        float mv[9];
        mv[0] = (vym && vxm) ? mbp[-W_ - 1] : 0.f;
        mv[1] = vym ? mbp[-W_] : 0.f;
        mv[2] = (vym && vxp) ? mbp[-W_ + 1] : 0.f;
        mv[3] = vxm ? mbp[-1] : 0.f;
        mv[4] = mbp[0];
        mv[5] = vxp ? mbp[1] : 0.f;
        mv[6] = (vyp && vxm) ? mbp[W_ - 1] : 0.f;
        mv[7] = vyp ? mbp[W_] : 0.f;
        mv[8] = (vyp && vxp) ? mbp[W_ + 1] : 0.f;
        float off[18], mm[9];
        #pragma unroll
        for (int o = 0; o < 18; ++o) off[o] = reg_b[o];
        #pragma unroll
        for (int k = 0; k < 9; ++k) mm[k] = m1_b[k];
        #pragma unroll
        for (int tt = 0; tt < 9; ++tt) {
            float vt = mv[tt];
            #pragma unroll
            for (int o = 0; o < 18; ++o) off[o] += vt * reg_w[o * 9 + tt];
            #pragma unroll
            for (int k = 0; k < 9; ++k) mm[k] += vt * m1_w[k * 9 + tt];
        }
        short o16[32];
        #pragma unroll
        for (int o = 0; o < 18; ++o) o16[o] = f2h(off[o]);
        #pragma unroll
        for (int k = 0; k < 9; ++k) o16[18 + k] = f2h(1.f / (1.f + __expf(-mm[k])));
        #pragma unroll
        for (int j = 27; j < 32; ++j) o16[j] = 0;
        short* dst = roff + (size_t)pix * 32;
        #pragma unroll
        for (int qd = 0; qd < 4; ++qd)
            *(bf16x8*)&dst[qd * 8] = *(const bf16x8*)&o16[qd * 8];
        return;
    }
    int i = (bid - NB_NHWC) * 256 + tid;
    if (i < 18 * 4 * 64 * 8) {
        int j = i & 7, lane = (i >> 3) & 63, nt = (i >> 9) & 3, gk = i >> 11;
        int n = lane & 15, q = lane >> 4;
        int o = nt * 16 + n;
        int g = gk / 9, k = gk - g * 9;
        int cin = g * CG_ + q * 8 + j;
        wbm[i] = f2h(weight[(o * CIN + cin) * 9 + k]);
        return;
    }
    int ii = i - 18 * 4 * 64 * 8;
    if (ii >= 18 * 2 * 64 * 8) return;
    int j = ii & 7, lane = (ii >> 3) & 63, nt = (ii >> 9) & 1, s = ii >> 10;
    int t_ = s >> 1, h = s & 1;
    int n = lane & 15, q = lane >> 4;
    int o = nt * 16 + n;
    int c = h * 32 + q * 8 + j;
    float v = 0.f;
    if (o < 18)      v = sem_w[(o * CIN + c) * 9 + t_];
    else if (o < 27) v = m2_w[((o - 18) * CIN + c) * 9 + t_];
    wbs[ii] = f2h(v);
}

// ---------------------------------------------------------------------------
// Phase-M K-step body, fp16 packed bilinear, weights given as regs/exprs.
// NAMED accumulators ma00..ma13 — indexed acc arrays miscompile here.
// ---------------------------------------------------------------------------
#define MBODY(GK, I0, I1, WB0, WB1, WB2, WB3) { \
    u32x4 d00 = *(const u32x4*)&pb[(I0)]; \
    u32x4 d01 = *(const u32x4*)&pb[(I0) + PST]; \
    u32x4 d10 = *(const u32x4*)&pb[(I0) + PC_ * PST]; \
    u32x4 d11 = *(const u32x4*)&pb[(I0) + (PC_ + 1) * PST]; \
    u32x4 e00 = *(const u32x4*)&pb[(I1)]; \
    u32x4 e01 = *(const u32x4*)&pb[(I1) + PST]; \
    u32x4 e10 = *(const u32x4*)&pb[(I1) + PC_ * PST]; \
    u32x4 e11 = *(const u32x4*)&pb[(I1) + (PC_ + 1) * PST]; \
    const uint2 mw0 = meta_w[(GK) * 32 + n]; \
    const uint2 mw1 = meta_w[(GK) * 32 + 16 + n]; \
    __half2 v00 = bcl(mw0.x), v01 = bch(mw0.x), v10 = bcl(mw0.y), v11 = bch(mw0.y); \
    __half2 u00 = bcl(mw1.x), u01 = bch(mw1.x), u10 = bcl(mw1.y), u11 = bch(mw1.y); \
    u32x4 ra, rb; \
    _Pragma("unroll") \
    for (int jj = 0; jj < 4; ++jj) { \
        __half2 s = __hfma2(H2(d00[jj]), v00, __hfma2(H2(d01[jj]), v01, \
                    __hfma2(H2(d10[jj]), v10, __hmul2(H2(d11[jj]), v11)))); \
        ra[jj] = __builtin_bit_cast(unsigned, s); \
        __half2 t = __hfma2(H2(e00[jj]), u00, __hfma2(H2(e01[jj]), u01, \
                    __hfma2(H2(e10[jj]), u10, __hmul2(H2(e11[jj]), u11)))); \
        rb[jj] = __builtin_bit_cast(unsigned, t); \
    } \
    f16x8 a0 = __builtin_bit_cast(f16x8, ra); \
    f16x8 a1 = __builtin_bit_cast(f16x8, rb); \
    ma00 = __builtin_amdgcn_mfma_f32_16x16x32_f16(a0, WB0, ma00, 0, 0, 0); \
    ma01 = __builtin_amdgcn_mfma_f32_16x16x32_f16(a0, WB1, ma01, 0, 0, 0); \
    ma02 = __builtin_amdgcn_mfma_f32_16x16x32_f16(a0, WB2, ma02, 0, 0, 0); \
    ma03 = __builtin_amdgcn_mfma_f32_16x16x32_f16(a0, WB3, ma03, 0, 0, 0); \
    ma10 = __builtin_amdgcn_mfma_f32_16x16x32_f16(a1, WB0, ma10, 0, 0, 0); \
    ma11 = __builtin_amdgcn_mfma_f32_16x16x32_f16(a1, WB1, ma11, 0, 0, 0); \
    ma12 = __builtin_amdgcn_mfma_f32_16x16x32_f16(a1, WB2, ma12, 0, 0, 0); \
    ma13 = __builtin_amdgcn_mfma_f32_16x16x32_f16(a1, WB3, ma13, 0, 0, 0); \
}

// Self-loading step (weights loaded first — vmcnt lands under the LDS window).
#define MSTEPP(GK, I0, I1) { \
    f16x8 wb0 = ((const f16x8*)wbm)[((GK) * 4 + 0) * 64 + lane]; \
    f16x8 wb1 = ((const f16x8*)wbm)[((GK) * 4 + 1) * 64 + lane]; \
    f16x8 wb2 = ((const f16x8*)wbm)[((GK) * 4 + 2) * 64 + lane]; \
    f16x8 wb3 = ((const f16x8*)wbm)[((GK) * 4 + 3) * 64 + lane]; \
    MBODY(GK, I0, I1, wb0, wb1, wb2, wb3) \
}

#define LIDX(GK, S) \
    const int i0_##S = (int)meta_i[(GK) * 32 + n] * PST; \
    const int i1_##S = (int)meta_i[(GK) * 32 + 16 + n] * PST;

// um reduction: only wave 0 (tid<32) -> lives in the kh==0 branch.
#define UMRED { if (tid < 32) { \
    float s_ = ums[tid] + ums[32 + tid] + ums[64 + tid] + ums[96 + tid]; \
    float u_ = fminf(fmaxf(64.f * s_, 0.f), 1.f); \
    um_out[(size_t)b * HW_ + y * W_ + x0 + tid] = u_; \
    umv[tid] = u_; } }

// Parallel dump: each wave writes its own region (overlaid on dead patch).
#define DUMP() { \
    float* dw = dout + w * (32 * DSTR); \
    _Pragma("unroll") \
    for (int r = 0; r < 4; ++r) { \
        dw[(q * 4 + r) * DSTR +  0 + n] = ma00[r]; \
        dw[(q * 4 + r) * DSTR + 16 + n] = ma01[r]; \
        dw[(q * 4 + r) * DSTR + 32 + n] = ma02[r]; \
        dw[(q * 4 + r) * DSTR + 48 + n] = ma03[r]; \
        dw[(16 + q * 4 + r) * DSTR +  0 + n] = ma10[r]; \
        dw[(16 + q * 4 + r) * DSTR + 16 + n] = ma11[r]; \
        dw[(16 + q * 4 + r) * DSTR + 32 + n] = ma12[r]; \
        dw[(16 + q * 4 + r) * DSTR + 48 + n] = ma13[r]; \
    } \
}

// ---------------------------------------------------------------------------
// Kernel C: fused, 32-px tile, 256 threads = 2 teams x 2 khalf waves.
// LDS 49568 B -> 3 blocks/CU; __launch_bounds__(256,3).
// g==0 offsets/dm now PRELOADED from roff (prep-computed) — no mask stencil,
// no 135-FMA conv, no sigmoid in fused's g0 slice.
// ---------------------------------------------------------------------------
__global__ __launch_bounds__(256, 3)
void fused_kernel(const short* __restrict__ inpT,
                  const float* __restrict__ mask_in,
                  const short* __restrict__ wbs,
                  const short* __restrict__ wbm,
                  const short* __restrict__ roff,
                  const float* __restrict__ sem_b,
                  const float* __restrict__ m2_b,
                  const float* __restrict__ bias,
                  float* __restrict__ out, float* __restrict__ um_out) {
    __shared__ __align__(16) short patch[PR_ * PC_ * PST];   // 38304 B; dout overlay
    __shared__ __align__(16) short redh[2 * 32 * RST];        // 4864 B (fp16)
    __shared__ __align__(8) uint2 meta_w[18 * 32];            // 4608 B
    __shared__ unsigned short meta_i[18 * 32];                // 1152 B
    __shared__ float ums[4 * 32];
    __shared__ float umv[32];
    float* dout = (float*)patch;    // 4 regions x 32*DSTR floats = 35328 B <= 38304

    const int tid  = threadIdx.x;
    const int lane = tid & 63;
    const int w    = __builtin_amdgcn_readfirstlane(tid >> 6);   // 0..3
    const int team = w >> 1;                  // offset group g
    const int kh   = w & 1;
    const int n = lane & 15, q = lane >> 4;

    // XCD band swizzle: 2304 blocks = 8 bands x 288
    const int bid  = blockIdx.x;
    const int band = bid & 7;
    const int jb   = bid >> 3;                // 0..287
    const int xt   = jb % XT_;
    const int rr   = band * 48 + jb / XT_;    // 0..383
    const int y    = rr % H_;
    const int b    = rr / H_;
    const int x0   = xt * PIX;

    // ====== prefetch phase-O weights (18x16B/lane; overlaps patch load) =====
    f16x8 wbsr[18];
    #pragma unroll
    for (int ss = 0; ss < 9; ++ss) {
        int s = team * 9 + ss;
        wbsr[ss * 2 + 0] = ((const f16x8*)wbs)[(s * 2 + 0) * 64 + lane];
        wbsr[ss * 2 + 1] = ((const f16x8*)wbs)[(s * 2 + 1) * 64 + lane];
    }

    // ====== phase P (core): rows 2..4 — all phase O needs ======
    for (int i = tid; i < 3 * PC_ * 8; i += 256) {
        int chunk = i & 7;
        int cc = (i >> 3) % PC_;
        int rp = 2 + (i >> 3) / PC_;
        int yy = y - 3 + rp;
        int xx = x0 - 3 + cc;
        bf16x8 v = {0, 0, 0, 0, 0, 0, 0, 0};
        if (yy >= 0 && yy < H_ && xx >= 0 && xx < W_)
            v = *(const bf16x8*)&inpT[((size_t)(b * HW_ + yy * W_ + xx)) * 64 + chunk * 8];
        *(bf16x8*)&patch[(rp * PC_ + cc) * PST + chunk * 8] = v;
    }
    __syncthreads();   // B0: core rows ready

    // ====== phase P (remainder): rows 0,1,5,6 — hides under phase O ======
    for (int j = tid; j < 4 * PC_ * 8; j += 256) {
        int chunk = j & 7;
        int cc = (j >> 3) % PC_;
        int rr4 = (j >> 3) / PC_;
        int rp = rr4 + ((rr4 >= 2) ? 3 : 0);          // 0,1,5,6
        int yy = y - 3 + rp;
        int xx = x0 - 3 + cc;
        bf16x8 v = {0, 0, 0, 0, 0, 0, 0, 0};
        if (yy >= 0 && yy < H_ && xx >= 0 && xx < W_)
            v = *(const bf16x8*)&inpT[((size_t)(b * HW_ + yy * W_ + xx)) * 64 + chunk * 8];
        *(bf16x8*)&patch[(rp * PC_ + cc) * PST + chunk * 8] = v;
    }

    // ====== phase O: sem+m2 conv via MFMA (reads rows 2-4 only) ======
    f32x4 acc0 = {0.f, 0.f, 0.f, 0.f}, acc1 = {0.f, 0.f, 0.f, 0.f};
    #pragma unroll
    for (int ss = 0; ss < 9; ++ss) {
        int s = team * 9 + ss;
        int tt = s >> 1, hh = s & 1;
        int dy = tt / 3 - 1, dx = tt % 3 - 1;
        int r = dy + 3;
        int c = kh * 16 + n + dx + 3;
        f16x8 a = *(const f16x8*)&patch[(r * PC_ + c) * PST + hh * 32 + q * 8];
        acc0 = __builtin_amdgcn_mfma_f32_16x16x32_f16(a, wbsr[ss * 2 + 0], acc0, 0, 0, 0);
        acc1 = __builtin_amdgcn_mfma_f32_16x16x32_f16(a, wbsr[ss * 2 + 1], acc1, 0, 0, 0);
    }
    // redh[team][pixel row 0..31][output 0..26] fp16, stride 38 (conflict-free)
    #pragma unroll
    for (int r = 0; r < 4; ++r) {
        redh[team * (32 * RST) + (kh * 16 + q * 4 + r) * RST + n]      = f2h(acc0[r]);
        redh[team * (32 * RST) + (kh * 16 + q * 4 + r) * RST + 16 + n] = f2h(acc1[r]);
    }
    __syncthreads();   // B1: redh + remainder patch rows ready

    // ====== prefetch first-two-step wbm (hides under phase 3 VALU) ======
    f16x8 pw0, pw1, pw2, pw3, pw4, pw5, pw6, pw7;
    {
        const int gk0 = team * 9 + (kh ? 5 : 0);
        pw0 = ((const f16x8*)wbm)[((gk0) * 4 + 0) * 64 + lane];
        pw1 = ((const f16x8*)wbm)[((gk0) * 4 + 1) * 64 + lane];
        pw2 = ((const f16x8*)wbm)[((gk0) * 4 + 2) * 64 + lane];
        pw3 = ((const f16x8*)wbm)[((gk0) * 4 + 3) * 64 + lane];
        pw4 = ((const f16x8*)wbm)[((gk0 + 1) * 4 + 0) * 64 + lane];
        pw5 = ((const f16x8*)wbm)[((gk0 + 1) * 4 + 1) * 64 + lane];
        pw6 = ((const f16x8*)wbm)[((gk0 + 1) * 4 + 2) * 64 + lane];
        pw7 = ((const f16x8*)wbm)[((gk0 + 1) * 4 + 3) * 64 + lane];
    }

    // ====== phase 3 (ALL 4 waves, kh-sliced): offsets/modulation/umask =====
    {
        const int g    = team;
        const int half = lane >> 5;
        const int pxl  = lane & 31;
        const int xl   = x0 + pxl;
        const int pixl = y * W_ + xl;
        const int qk = (kh << 1) | half;                       // 0..3 k-quarter
        const int k0 = (qk == 0) ? 0 : (qk == 1) ? 3 : (qk == 2) ? 5 : 7;
        const int k1 = (qk == 0) ? 3 : (qk == 1) ? 5 : (qk == 2) ? 7 : 9;
        float off_[18], dmv[9];
        if (g == 0) {
            // preloaded region offsets + pre-sigmoided dm (prep-computed)
            const unsigned short* rb16 =
                (const unsigned short*)&roff[((size_t)b * HW_ + pixl) * 32];
            if (kh == 0) {
                u32x4 q0 = *(const u32x4*)&rb16[0];
                u32x4 q1 = *(const u32x4*)&rb16[8];
                u32x4 q2 = *(const u32x4*)&rb16[16];
                #pragma unroll
                for (int o = 0; o < 8; ++o) off_[o] = hx(q0, o);
                off_[8] = hx(q1, 0); off_[9] = hx(q1, 1);
                #pragma unroll
                for (int k = 0; k < 5; ++k) dmv[k] = hx(q2, 2 + k);
            } else {
                u32x4 q1 = *(const u32x4*)&rb16[8];
                u32x4 q2 = *(const u32x4*)&rb16[16];
                u32x4 q3 = *(const u32x4*)&rb16[24];
                #pragma unroll
                for (int o = 0; o < 6; ++o) off_[10 + o] = hx(q1, 2 + o);
                off_[16] = hx(q2, 0); off_[17] = hx(q2, 1);
                dmv[5] = hx(q2, 7);
                dmv[6] = hx(q3, 0); dmv[7] = hx(q3, 1); dmv[8] = hx(q3, 2);
            }
        } else {
            if (kh == 0) {
                #pragma unroll
                for (int o = 0; o < 10; ++o)
                    off_[o] = h2f(redh[pxl * RST + o]) + h2f(redh[32 * RST + pxl * RST + o]) + sem_b[o];
                #pragma unroll
                for (int k = 0; k < 5; ++k) {
                    float mmk = h2f(redh[pxl * RST + 18 + k]) + h2f(redh[32 * RST + pxl * RST + 18 + k]) + m2_b[k];
                    dmv[k] = 1.f / (1.f + __expf(-mmk));
                }
            } else {
                #pragma unroll
                for (int o = 10; o < 18; ++o)
                    off_[o] = h2f(redh[pxl * RST + o]) + h2f(redh[32 * RST + pxl * RST + o]) + sem_b[o];
                #pragma unroll
                for (int k = 5; k < 9; ++k) {
                    float mmk = h2f(redh[pxl * RST + 18 + k]) + h2f(redh[32 * RST + pxl * RST + 18 + k]) + m2_b[k];
                    dmv[k] = 1.f / (1.f + __expf(-mmk));
                }
            }
        }

        const float* mb = mask_in + (size_t)b * HW_;
        float s_um = 0.f;
        #pragma unroll
        for (int k = 0; k < 9; ++k) {
            if (k < k0 || k >= k1) continue;
            float Y = off_[2 * k]     + (float)y  + (float)(k / 3 - 1);
            float X = off_[2 * k + 1] + (float)xl + (float)(k % 3 - 1);
            int gk = g * 9 + k;
            float dm = dmv[k];
            float y0f = floorf(Y), x0f = floorf(X);
            int yi0 = (int)y0f, xi0 = (int)x0f;
            float ly = Y - y0f, lx = X - x0f;
            int yi1 = yi0 + 1, xi1 = xi0 + 1;
            bool vy0 = (yi0 >= 0 && yi0 < H_), vy1 = (yi1 >= 0 && yi1 < H_);
            bool vx0 = (xi0 >= 0 && xi0 < W_), vx1 = (xi1 >= 0 && xi1 < W_);
            float w00f = (vy0 && vx0) ? (1.f - ly) * (1.f - lx) : 0.f;
            float w01f = (vy0 && vx1) ? (1.f - ly) * lx : 0.f;
            float w10f = (vy1 && vx0) ? ly * (1.f - lx) : 0.f;
            float w11f = (vy1 && vx1) ? ly * lx : 0.f;
            int yc0 = min(max(yi0, 0), H_ - 1), yc1 = min(max(yi1, 0), H_ - 1);
            int xc0 = min(max(xi0, 0), W_ - 1), xc1 = min(max(xi1, 0), W_ - 1);
            // umask bilinear (global mask reads, L1-hot)
            s_um += w00f * mb[yc0 * W_ + xc0] + w01f * mb[yc0 * W_ + xc1]
                  + w10f * mb[yc1 * W_ + xc0] + w11f * mb[yc1 * W_ + xc1];
            // patch-local corner-00 (UNclamped coords map into the zero-padded
            // patch for |off|<2; clamp only as out-of-distribution safety)
            int r0 = min(max(yi0 - (y - 3), 0), PR_ - 2);     // 0..5
            int c0 = min(max(xi0 - (x0 - 3), 0), PC_ - 2);    // 0..36
            meta_w[gk * 32 + pxl] = make_uint2(pk2hu(w00f * dm, w01f * dm),
                                               pk2hu(w10f * dm, w11f * dm));
            meta_i[gk * 32 + pxl] = (unsigned short)(r0 * PC_ + c0);
        }
        s_um += __shfl_xor(s_um, 32);
        if (half == 0) ums[w * 32 + pxl] = s_um;
    }
    __syncthreads();   // B2: meta + ums ready

    // ====== phase M: main conv; wave (team, khalf) owns gk subset ===========
    f32x4 ma00 = {0.f,0.f,0.f,0.f}, ma01 = {0.f,0.f,0.f,0.f};
    f32x4 ma02 = {0.f,0.f,0.f,0.f}, ma03 = {0.f,0.f,0.f,0.f};
    f32x4 ma10 = {0.f,0.f,0.f,0.f}, ma11 = {0.f,0.f,0.f,0.f};
    f32x4 ma12 = {0.f,0.f,0.f,0.f}, ma13 = {0.f,0.f,0.f,0.f};
    {
        const short* pb = patch + team * 32 + q * 8;
        const int t9 = team * 9;
        if (kh == 0) {
            LIDX(t9 + 0, 0) LIDX(t9 + 1, 1) LIDX(t9 + 2, 2) LIDX(t9 + 3, 3) LIDX(t9 + 4, 4)
            UMRED
            MBODY(t9 + 0, i0_0, i1_0, pw0, pw1, pw2, pw3)
            MBODY(t9 + 1, i0_1, i1_1, pw4, pw5, pw6, pw7)
            MSTEPP(t9 + 2, i0_2, i1_2)
            MSTEPP(t9 + 3, i0_3, i1_3)
            MSTEPP(t9 + 4, i0_4, i1_4)
        } else {
            LIDX(t9 + 5, 0) LIDX(t9 + 6, 1) LIDX(t9 + 7, 2) LIDX(t9 + 8, 3)
            MBODY(t9 + 5, i0_0, i1_0, pw0, pw1, pw2, pw3)
            MBODY(t9 + 6, i0_1, i1_1, pw4, pw5, pw6, pw7)
            MSTEPP(t9 + 7, i0_2, i1_2)
            MSTEPP(t9 + 8, i0_3, i1_3)
        }
    }
    __syncthreads();   // B3: all waves done reading patch -> overlay dout

    DUMP();            // all 4 waves in parallel, private regions
    __syncthreads();   // B4: dout + umv ready

    // epilogue: sum 4 wave-partials, coalesced stores
    {
        const int pxs = tid & 31;
        const int o0  = (tid >> 5) * 8;
        float u = umv[pxs];
        float* ob = out + ((size_t)b * COUT + o0) * HW_ + y * W_ + x0 + pxs;
        const float* bs = bias + o0;
        const float* dp = dout + pxs * DSTR + o0;
        #pragma unroll
        for (int o = 0; o < 8; ++o)
            ob[(size_t)o * HW_] = (dp[o] + dp[32 * DSTR + o] + dp[2 * 32 * DSTR + o]
                                   + dp[3 * 32 * DSTR + o] + bs[o]) * u;
    }
}

// ---------------------------------------------------------------------------
extern "C" void kernel_launch(void* const* d_in, const int* in_sizes, int n_in,
                              void* d_out, int out_size, void* d_ws, size_t ws_size,
                              hipStream_t stream) {
    const float* input   = (const float*)d_in[0];
    const float* mask_in = (const float*)d_in[1];
    const float* weight  = (const float*)d_in[2];
    const float* bias    = (const float*)d_in[3];
    const float* sem_w   = (const float*)d_in[4];
    const float* sem_b   = (const float*)d_in[5];
    const float* reg_w   = (const float*)d_in[6];
    const float* reg_b   = (const float*)d_in[7];
    const float* m1_w    = (const float*)d_in[8];
    const float* m1_b    = (const float*)d_in[9];
    const float* m2_w    = (const float*)d_in[10];
    const float* m2_b    = (const float*)d_in[11];

    float* out = (float*)d_out;                        // (B,COUT,H,W)
    float* um  = out + (size_t)B_ * COUT * HW_;        // (B,1,H,W)

    short* inpT = (short*)d_ws;                        // B*HW*64
    short* wbm  = inpT + (size_t)B_ * HW_ * 64;        // 36,864 shorts
    short* wbs  = wbm + 18 * 4 * 64 * 8;               // 18,432 shorts
    short* roff = wbs + 18 * 2 * 64 * 8;               // B*HW*32 shorts (4.7 MB)

    prep_kernel<<<NB_NHWC + NB_WT + NB_RO, 256, 0, stream>>>(
        input, weight, sem_w, m2_w, mask_in, reg_w, reg_b, m1_w, m1_b,
        inpT, wbm, wbs, roff);
    fused_kernel<<<B_ * H_ * XT_, 256, 0, stream>>>(
        inpT, mask_in, wbs, wbm, roff, sem_b, m2_b,
        bias, out, um);
}

// Round 7
// 127.390 us; speedup vs baseline: 1.0385x; 1.0385x over previous
//
#include <hip/hip_runtime.h>
#include <hip/hip_fp16.h>
#include <math.h>

#define B_  2
#define CIN 64
#define COUT 64
#define H_  192
#define W_  192
#define G_  2
#define KK_ 9
#define CG_ 32
#define HW_ (H_*W_)
#define PIX 32            // pixels per block (x-contiguous)
#define XT_ (W_/PIX)      // 6 x-tiles per row
#define PR_ 7             // patch rows (y-3 .. y+3)
#define PC_ 38            // patch cols (x0-3 .. x0+34)
#define PST 72            // patch row stride in shorts (64 ch + 8 pad)
#define DSTR 69           // dout row stride in floats (bank-spread)
#define RST 38            // redh row stride in shorts (conflict-free: 19 odd)
#define NB_NHWC (B_ * (HW_ / 64))        // 1152
#define NB_WT   ((18*4*64*8 + 18*2*64*8) / 256)   // 216

typedef __attribute__((ext_vector_type(8))) short bf16x8;      // 8x16-bit container
typedef __attribute__((ext_vector_type(8))) _Float16 f16x8;
typedef __attribute__((ext_vector_type(4))) unsigned int u32x4;
typedef __attribute__((ext_vector_type(4))) float f32x4;

static __device__ __forceinline__ short f2h(float f) {
    _Float16 h = (_Float16)f;
    return __builtin_bit_cast(short, h);
}
static __device__ __forceinline__ float h2f(short s) {
    _Float16 h = __builtin_bit_cast(_Float16, s);
    return (float)h;
}
static __device__ __forceinline__ unsigned pk2hu(float lo, float hi) {
    auto h = __builtin_amdgcn_cvt_pkrtz(lo, hi);   // __fp16 ext_vector(2)
    return __builtin_bit_cast(unsigned, h);
}
static __device__ __forceinline__ short2 pk2h(float lo, float hi) {
    auto h = __builtin_amdgcn_cvt_pkrtz(lo, hi);
    return __builtin_bit_cast(short2, h);
}
static __device__ __forceinline__ __half2 bcl(unsigned u) {      // broadcast low half
    return __builtin_bit_cast(__half2, (unsigned)((u & 0xffffu) | (u << 16)));
}
static __device__ __forceinline__ __half2 bch(unsigned u) {      // broadcast high half
    return __builtin_bit_cast(__half2, (unsigned)((u >> 16) | (u & 0xffff0000u)));
}
static __device__ __forceinline__ __half2 H2(unsigned u) {
    return __builtin_bit_cast(__half2, u);
}

// ---------------------------------------------------------------------------
// Kernel A: prep — NCHW->NHWC fp16 transform + weight pack (fp16).
// ---------------------------------------------------------------------------
__global__ __launch_bounds__(256)
void prep_kernel(const float* __restrict__ in,
                 const float* __restrict__ weight,
                 const float* __restrict__ sem_w,
                 const float* __restrict__ m2_w,
                 short* __restrict__ inpT,
                 short* __restrict__ wbm,
                 short* __restrict__ wbs) {
    __shared__ float t[64][65];
    const int tid = threadIdx.x;
    const int bid = blockIdx.x;
    if (bid < NB_NHWC) {
        const int b = bid / (HW_ / 64);
        const int pix0 = (bid % (HW_ / 64)) * 64;
        const float* src = in + (size_t)b * CIN * HW_ + pix0;
        const int c0 = (tid >> 6) * 16;
        const int p  = tid & 63;
        #pragma unroll
        for (int i = 0; i < 16; ++i)
            t[c0 + i][p] = src[(size_t)(c0 + i) * HW_ + p];
        __syncthreads();
        short* dst = inpT + ((size_t)b * HW_ + pix0) * 64;
        #pragma unroll
        for (int i = 0; i < 2; ++i) {
            int item = i * 256 + tid;
            int pp = item >> 3, oct = item & 7;
            bf16x8 v;
            #pragma unroll
            for (int j = 0; j < 8; j += 2) {
                short2 ss = pk2h(t[oct * 8 + j][pp], t[oct * 8 + j + 1][pp]);
                v[j] = ss.x; v[j + 1] = ss.y;
            }
            *(bf16x8*)&dst[pp * 64 + oct * 8] = v;
        }
        return;
    }
    int i = (bid - NB_NHWC) * 256 + tid;
    if (i < 18 * 4 * 64 * 8) {
        int j = i & 7, lane = (i >> 3) & 63, nt = (i >> 9) & 3, gk = i >> 11;
        int n = lane & 15, q = lane >> 4;
        int o = nt * 16 + n;
        int g = gk / 9, k = gk - g * 9;
        int cin = g * CG_ + q * 8 + j;
        wbm[i] = f2h(weight[(o * CIN + cin) * 9 + k]);
        return;
    }
    int ii = i - 18 * 4 * 64 * 8;
    if (ii >= 18 * 2 * 64 * 8) return;
    int j = ii & 7, lane = (ii >> 3) & 63, nt = (ii >> 9) & 1, s = ii >> 10;
    int t_ = s >> 1, h = s & 1;
    int n = lane & 15, q = lane >> 4;
    int o = nt * 16 + n;
    int c = h * 32 + q * 8 + j;
    float v = 0.f;
    if (o < 18)      v = sem_w[(o * CIN + c) * 9 + t_];
    else if (o < 27) v = m2_w[((o - 18) * CIN + c) * 9 + t_];
    wbs[ii] = f2h(v);
}

// ---------------------------------------------------------------------------
// Phase-M K-step body, fp16 packed bilinear, weights given as regs/exprs.
// NAMED accumulators ma00..ma13 — indexed acc arrays miscompile here.
// ---------------------------------------------------------------------------
#define MBODY(GK, I0, I1, WB0, WB1, WB2, WB3) { \
    u32x4 d00 = *(const u32x4*)&pb[(I0)]; \
    u32x4 d01 = *(const u32x4*)&pb[(I0) + PST]; \
    u32x4 d10 = *(const u32x4*)&pb[(I0) + PC_ * PST]; \
    u32x4 d11 = *(const u32x4*)&pb[(I0) + (PC_ + 1) * PST]; \
    u32x4 e00 = *(const u32x4*)&pb[(I1)]; \
    u32x4 e01 = *(const u32x4*)&pb[(I1) + PST]; \
    u32x4 e10 = *(const u32x4*)&pb[(I1) + PC_ * PST]; \
    u32x4 e11 = *(const u32x4*)&pb[(I1) + (PC_ + 1) * PST]; \
    const uint2 mw0 = meta_w[(GK) * 32 + n]; \
    const uint2 mw1 = meta_w[(GK) * 32 + 16 + n]; \
    __half2 v00 = bcl(mw0.x), v01 = bch(mw0.x), v10 = bcl(mw0.y), v11 = bch(mw0.y); \
    __half2 u00 = bcl(mw1.x), u01 = bch(mw1.x), u10 = bcl(mw1.y), u11 = bch(mw1.y); \
    u32x4 ra, rb; \
    _Pragma("unroll") \
    for (int jj = 0; jj < 4; ++jj) { \
        __half2 s = __hfma2(H2(d00[jj]), v00, __hfma2(H2(d01[jj]), v01, \
                    __hfma2(H2(d10[jj]), v10, __hmul2(H2(d11[jj]), v11)))); \
        ra[jj] = __builtin_bit_cast(unsigned, s); \
        __half2 t = __hfma2(H2(e00[jj]), u00, __hfma2(H2(e01[jj]), u01, \
                    __hfma2(H2(e10[jj]), u10, __hmul2(H2(e11[jj]), u11)))); \
        rb[jj] = __builtin_bit_cast(unsigned, t); \
    } \
    f16x8 a0 = __builtin_bit_cast(f16x8, ra); \
    f16x8 a1 = __builtin_bit_cast(f16x8, rb); \
    ma00 = __builtin_amdgcn_mfma_f32_16x16x32_f16(a0, WB0, ma00, 0, 0, 0); \
    ma01 = __builtin_amdgcn_mfma_f32_16x16x32_f16(a0, WB1, ma01, 0, 0, 0); \
    ma02 = __builtin_amdgcn_mfma_f32_16x16x32_f16(a0, WB2, ma02, 0, 0, 0); \
    ma03 = __builtin_amdgcn_mfma_f32_16x16x32_f16(a0, WB3, ma03, 0, 0, 0); \
    ma10 = __builtin_amdgcn_mfma_f32_16x16x32_f16(a1, WB0, ma10, 0, 0, 0); \
    ma11 = __builtin_amdgcn_mfma_f32_16x16x32_f16(a1, WB1, ma11, 0, 0, 0); \
    ma12 = __builtin_amdgcn_mfma_f32_16x16x32_f16(a1, WB2, ma12, 0, 0, 0); \
    ma13 = __builtin_amdgcn_mfma_f32_16x16x32_f16(a1, WB3, ma13, 0, 0, 0); \
}

// Self-loading step (weights loaded first — vmcnt lands under the LDS window).
#define MSTEPP(GK, I0, I1) { \
    f16x8 wb0 = ((const f16x8*)wbm)[((GK) * 4 + 0) * 64 + lane]; \
    f16x8 wb1 = ((const f16x8*)wbm)[((GK) * 4 + 1) * 64 + lane]; \
    f16x8 wb2 = ((const f16x8*)wbm)[((GK) * 4 + 2) * 64 + lane]; \
    f16x8 wb3 = ((const f16x8*)wbm)[((GK) * 4 + 3) * 64 + lane]; \
    MBODY(GK, I0, I1, wb0, wb1, wb2, wb3) \
}

#define LIDX(GK, S) \
    const int i0_##S = (int)meta_i[(GK) * 32 + n] * PST; \
    const int i1_##S = (int)meta_i[(GK) * 32 + 16 + n] * PST;

// um reduction: only wave 0 (tid<32) -> lives in the kh==0 branch.
#define UMRED { if (tid < 32) { \
    float s_ = ums[tid] + ums[32 + tid] + ums[64 + tid] + ums[96 + tid]; \
    float u_ = fminf(fmaxf(64.f * s_, 0.f), 1.f); \
    um_out[(size_t)b * HW_ + y * W_ + x0 + tid] = u_; \
    umv[tid] = u_; } }

// Parallel dump: each wave writes its own region (overlaid on dead patch).
#define DUMP() { \
    float* dw = dout + w * (32 * DSTR); \
    _Pragma("unroll") \
    for (int r = 0; r < 4; ++r) { \
        dw[(q * 4 + r) * DSTR +  0 + n] = ma00[r]; \
        dw[(q * 4 + r) * DSTR + 16 + n] = ma01[r]; \
        dw[(q * 4 + r) * DSTR + 32 + n] = ma02[r]; \
        dw[(q * 4 + r) * DSTR + 48 + n] = ma03[r]; \
        dw[(16 + q * 4 + r) * DSTR +  0 + n] = ma10[r]; \
        dw[(16 + q * 4 + r) * DSTR + 16 + n] = ma11[r]; \
        dw[(16 + q * 4 + r) * DSTR + 32 + n] = ma12[r]; \
        dw[(16 + q * 4 + r) * DSTR + 48 + n] = ma13[r]; \
    } \
}

// Phase-3 sliced offset/modulation compute (kh-uniform slice [OL,OH)/[ML,MH)).
#define COMPOFF(OL, OH, ML, MH) { \
    if (g == 0) { \
        _Pragma("unroll") for (int o = (OL); o < (OH); ++o) off_[o] = reg_b[o]; \
        _Pragma("unroll") for (int k = (ML); k < (MH); ++k) mm[k] = m1_b[k]; \
        _Pragma("unroll") for (int t = 0; t < 9; ++t) { \
            float vt = mv[t]; \
            _Pragma("unroll") for (int o = (OL); o < (OH); ++o) off_[o] += vt * reg_w[o * 9 + t]; \
            _Pragma("unroll") for (int k = (ML); k < (MH); ++k) mm[k] += vt * m1_w[k * 9 + t]; \
        } \
    } else { \
        _Pragma("unroll") for (int o = (OL); o < (OH); ++o) \
            off_[o] = h2f(redh[pxl * RST + o]) + h2f(redh[32 * RST + pxl * RST + o]) + sem_b[o]; \
        _Pragma("unroll") for (int k = (ML); k < (MH); ++k) \
            mm[k] = h2f(redh[pxl * RST + 18 + k]) + h2f(redh[32 * RST + pxl * RST + 18 + k]) + m2_b[k]; \
    } \
}

// ---------------------------------------------------------------------------
// Kernel C: fused, 32-px tile, 256 threads = 2 teams x 2 khalf waves.
// LDS 49568 B -> 3 blocks/CU; __launch_bounds__(256,3) caps VGPR ~168 (free).
// Phase P split: core rows 2-4 first (phase O reads only those), remainder
// rows 0,1,5,6 issued after B0 -> VMEM hides under phase O MFMA (fenced @ B1).
// ---------------------------------------------------------------------------
__global__ __launch_bounds__(256, 3)
void fused_kernel(const short* __restrict__ inpT,
                  const float* __restrict__ mask_in,
                  const short* __restrict__ wbs,
                  const short* __restrict__ wbm,
                  const float* __restrict__ sem_b,
                  const float* __restrict__ reg_w, const float* __restrict__ reg_b,
                  const float* __restrict__ m1_w, const float* __restrict__ m1_b,
                  const float* __restrict__ m2_b,
                  const float* __restrict__ bias,
                  float* __restrict__ out, float* __restrict__ um_out) {
    __shared__ __align__(16) short patch[PR_ * PC_ * PST];   // 38304 B; dout overlay
    __shared__ __align__(16) short redh[2 * 32 * RST];        // 4864 B (fp16)
    __shared__ __align__(8) uint2 meta_w[18 * 32];            // 4608 B
    __shared__ unsigned short meta_i[18 * 32];                // 1152 B
    __shared__ float ums[4 * 32];
    __shared__ float umv[32];
    float* dout = (float*)patch;    // 4 regions x 32*DSTR floats = 35328 B <= 38304

    const int tid  = threadIdx.x;
    const int lane = tid & 63;
    const int w    = __builtin_amdgcn_readfirstlane(tid >> 6);   // 0..3
    const int team = w >> 1;                  // offset group g
    const int kh   = w & 1;
    const int n = lane & 15, q = lane >> 4;

    // XCD band swizzle: 2304 blocks = 8 bands x 288
    const int bid  = blockIdx.x;
    const int band = bid & 7;
    const int jb   = bid >> 3;                // 0..287
    const int xt   = jb % XT_;
    const int rr   = band * 48 + jb / XT_;    // 0..383
    const int y    = rr % H_;
    const int b    = rr / H_;
    const int x0   = xt * PIX;

    // ====== prefetch phase-O weights (18x16B/lane; overlaps patch load) =====
    f16x8 wbsr[18];
    #pragma unroll
    for (int ss = 0; ss < 9; ++ss) {
        int s = team * 9 + ss;
        wbsr[ss * 2 + 0] = ((const f16x8*)wbs)[(s * 2 + 0) * 64 + lane];
        wbsr[ss * 2 + 1] = ((const f16x8*)wbs)[(s * 2 + 1) * 64 + lane];
    }

    // ====== phase P (core): rows 2..4 — all phase O needs ======
    for (int i = tid; i < 3 * PC_ * 8; i += 256) {
        int chunk = i & 7;
        int cc = (i >> 3) % PC_;
        int rp = 2 + (i >> 3) / PC_;
        int yy = y - 3 + rp;
        int xx = x0 - 3 + cc;
        bf16x8 v = {0, 0, 0, 0, 0, 0, 0, 0};
        if (yy >= 0 && yy < H_ && xx >= 0 && xx < W_)
            v = *(const bf16x8*)&inpT[((size_t)(b * HW_ + yy * W_ + xx)) * 64 + chunk * 8];
        *(bf16x8*)&patch[(rp * PC_ + cc) * PST + chunk * 8] = v;
    }
    __syncthreads();   // B0: core rows ready

    // ====== phase P (remainder): rows 0,1,5,6 — hides under phase O ======
    for (int j = tid; j < 4 * PC_ * 8; j += 256) {
        int chunk = j & 7;
        int cc = (j >> 3) % PC_;
        int rr4 = (j >> 3) / PC_;
        int rp = rr4 + ((rr4 >= 2) ? 3 : 0);          // 0,1,5,6
        int yy = y - 3 + rp;
        int xx = x0 - 3 + cc;
        bf16x8 v = {0, 0, 0, 0, 0, 0, 0, 0};
        if (yy >= 0 && yy < H_ && xx >= 0 && xx < W_)
            v = *(const bf16x8*)&inpT[((size_t)(b * HW_ + yy * W_ + xx)) * 64 + chunk * 8];
        *(bf16x8*)&patch[(rp * PC_ + cc) * PST + chunk * 8] = v;
    }

    // ====== phase O: sem+m2 conv via MFMA (reads rows 2-4 only) ======
    f32x4 acc0 = {0.f, 0.f, 0.f, 0.f}, acc1 = {0.f, 0.f, 0.f, 0.f};
    #pragma unroll
    for (int ss = 0; ss < 9; ++ss) {
        int s = team * 9 + ss;
        int tt = s >> 1, hh = s & 1;
        int dy = tt / 3 - 1, dx = tt % 3 - 1;
        int r = dy + 3;
        int c = kh * 16 + n + dx + 3;
        f16x8 a = *(const f16x8*)&patch[(r * PC_ + c) * PST + hh * 32 + q * 8];
        acc0 = __builtin_amdgcn_mfma_f32_16x16x32_f16(a, wbsr[ss * 2 + 0], acc0, 0, 0, 0);
        acc1 = __builtin_amdgcn_mfma_f32_16x16x32_f16(a, wbsr[ss * 2 + 1], acc1, 0, 0, 0);
    }
    // redh[team][pixel row 0..31][output 0..26] fp16, stride 38 (conflict-free)
    #pragma unroll
    for (int r = 0; r < 4; ++r) {
        redh[team * (32 * RST) + (kh * 16 + q * 4 + r) * RST + n]      = f2h(acc0[r]);
        redh[team * (32 * RST) + (kh * 16 + q * 4 + r) * RST + 16 + n] = f2h(acc1[r]);
    }
    __syncthreads();   // B1: redh + remainder patch rows ready

    // ====== prefetch first-two-step wbm (hides under phase 3 VALU) ======
    f16x8 pw0, pw1, pw2, pw3, pw4, pw5, pw6, pw7;
    {
        const int gk0 = team * 9 + (kh ? 5 : 0);
        pw0 = ((const f16x8*)wbm)[((gk0) * 4 + 0) * 64 + lane];
        pw1 = ((const f16x8*)wbm)[((gk0) * 4 + 1) * 64 + lane];
        pw2 = ((const f16x8*)wbm)[((gk0) * 4 + 2) * 64 + lane];
        pw3 = ((const f16x8*)wbm)[((gk0) * 4 + 3) * 64 + lane];
        pw4 = ((const f16x8*)wbm)[((gk0 + 1) * 4 + 0) * 64 + lane];
        pw5 = ((const f16x8*)wbm)[((gk0 + 1) * 4 + 1) * 64 + lane];
        pw6 = ((const f16x8*)wbm)[((gk0 + 1) * 4 + 2) * 64 + lane];
        pw7 = ((const f16x8*)wbm)[((gk0 + 1) * 4 + 3) * 64 + lane];
    }

    // ====== phase 3 (ALL 4 waves, kh-sliced): offsets/modulation/umask =====
    {
        const int g    = team;
        const int half = lane >> 5;
        const int pxl  = lane & 31;
        const int xl   = x0 + pxl;
        const int pixl = y * W_ + xl;
        const bool vxm = xl > 0, vxp = (xl + 1) < W_;
        const bool vym = y > 0,  vyp = (y + 1) < H_;
        const int qk = (kh << 1) | half;                       // 0..3 k-quarter
        const int k0 = (qk == 0) ? 0 : (qk == 1) ? 3 : (qk == 2) ? 5 : 7;
        const int k1 = (qk == 0) ? 3 : (qk == 1) ? 5 : (qk == 2) ? 7 : 9;
        float off_[18], mm[9];
        float mv[9];
        if (g == 0) {
            const float* mbp = mask_in + (size_t)b * HW_ + pixl;
            mv[0] = (vym && vxm) ? mbp[-W_ - 1] : 0.f;
            mv[1] = vym ? mbp[-W_] : 0.f;
            mv[2] = (vym && vxp) ? mbp[-W_ + 1] : 0.f;
            mv[3] = vxm ? mbp[-1] : 0.f;
            mv[4] = mbp[0];
            mv[5] = vxp ? mbp[1] : 0.f;
            mv[6] = (vyp && vxm) ? mbp[W_ - 1] : 0.f;
            mv[7] = vyp ? mbp[W_] : 0.f;
            mv[8] = (vyp && vxp) ? mbp[W_ + 1] : 0.f;
        }
        // kh is wave-uniform: each wave computes only the slice its k-range needs
        if (kh == 0) { COMPOFF(0, 10, 0, 5) } else { COMPOFF(10, 18, 5, 9) }

        const float* mb = mask_in + (size_t)b * HW_;
        float s_um = 0.f;
        #pragma unroll
        for (int k = 0; k < 9; ++k) {
            if (k < k0 || k >= k1) continue;
            float Y = off_[2 * k]     + (float)y  + (float)(k / 3 - 1);
            float X = off_[2 * k + 1] + (float)xl + (float)(k % 3 - 1);
            int gk = g * 9 + k;
            float dm = 1.f / (1.f + __expf(-mm[k]));
            float y0f = floorf(Y), x0f = floorf(X);
            int yi0 = (int)y0f, xi0 = (int)x0f;
            float ly = Y - y0f, lx = X - x0f;
            int yi1 = yi0 + 1, xi1 = xi0 + 1;
            bool vy0 = (yi0 >= 0 && yi0 < H_), vy1 = (yi1 >= 0 && yi1 < H_);
            bool vx0 = (xi0 >= 0 && xi0 < W_), vx1 = (xi1 >= 0 && xi1 < W_);
            float w00f = (vy0 && vx0) ? (1.f - ly) * (1.f - lx) : 0.f;
            float w01f = (vy0 && vx1) ? (1.f - ly) * lx : 0.f;
            float w10f = (vy1 && vx0) ? ly * (1.f - lx) : 0.f;
            float w11f = (vy1 && vx1) ? ly * lx : 0.f;
            int yc0 = min(max(yi0, 0), H_ - 1), yc1 = min(max(yi1, 0), H_ - 1);
            int xc0 = min(max(xi0, 0), W_ - 1), xc1 = min(max(xi1, 0), W_ - 1);
            // umask bilinear (global mask reads, L1-hot)
            s_um += w00f * mb[yc0 * W_ + xc0] + w01f * mb[yc0 * W_ + xc1]
                  + w10f * mb[yc1 * W_ + xc0] + w11f * mb[yc1 * W_ + xc1];
            // patch-local corner-00 (UNclamped coords map into the zero-padded
            // patch for |off|<2; clamp only as out-of-distribution safety)
            int r0 = min(max(yi0 - (y - 3), 0), PR_ - 2);     // 0..5
            int c0 = min(max(xi0 - (x0 - 3), 0), PC_ - 2);    // 0..36
            meta_w[gk * 32 + pxl] = make_uint2(pk2hu(w00f * dm, w01f * dm),
                                               pk2hu(w10f * dm, w11f * dm));
            meta_i[gk * 32 + pxl] = (unsigned short)(r0 * PC_ + c0);
        }
        s_um += __shfl_xor(s_um, 32);
        if (half == 0) ums[w * 32 + pxl] = s_um;
    }
    __syncthreads();   // B2: meta + ums ready

    // ====== phase M: main conv; wave (team, khalf) owns gk subset ===========
    f32x4 ma00 = {0.f,0.f,0.f,0.f}, ma01 = {0.f,0.f,0.f,0.f};
    f32x4 ma02 = {0.f,0.f,0.f,0.f}, ma03 = {0.f,0.f,0.f,0.f};
    f32x4 ma10 = {0.f,0.f,0.f,0.f}, ma11 = {0.f,0.f,0.f,0.f};
    f32x4 ma12 = {0.f,0.f,0.f,0.f}, ma13 = {0.f,0.f,0.f,0.f};
    {
        const short* pb = patch + team * 32 + q * 8;
        const int t9 = team * 9;
        if (kh == 0) {
            LIDX(t9 + 0, 0) LIDX(t9 + 1, 1) LIDX(t9 + 2, 2) LIDX(t9 + 3, 3) LIDX(t9 + 4, 4)
            UMRED
            MBODY(t9 + 0, i0_0, i1_0, pw0, pw1, pw2, pw3)
            MBODY(t9 + 1, i0_1, i1_1, pw4, pw5, pw6, pw7)
            MSTEPP(t9 + 2, i0_2, i1_2)
            MSTEPP(t9 + 3, i0_3, i1_3)
            MSTEPP(t9 + 4, i0_4, i1_4)
        } else {
            LIDX(t9 + 5, 0) LIDX(t9 + 6, 1) LIDX(t9 + 7, 2) LIDX(t9 + 8, 3)
            MBODY(t9 + 5, i0_0, i1_0, pw0, pw1, pw2, pw3)
            MBODY(t9 + 6, i0_1, i1_1, pw4, pw5, pw6, pw7)
            MSTEPP(t9 + 7, i0_2, i1_2)
            MSTEPP(t9 + 8, i0_3, i1_3)
        }
    }
    __syncthreads();   // B3: all waves done reading patch -> overlay dout

    DUMP();            // all 4 waves in parallel, private regions
    __syncthreads();   // B4: dout + umv ready

    // epilogue: sum 4 wave-partials, coalesced stores
    {
        const int pxs = tid & 31;
        const int o0  = (tid >> 5) * 8;
        float u = umv[pxs];
        float* ob = out + ((size_t)b * COUT + o0) * HW_ + y * W_ + x0 + pxs;
        const float* bs = bias + o0;
        const float* dp = dout + pxs * DSTR + o0;
        #pragma unroll
        for (int o = 0; o < 8; ++o)
            ob[(size_t)o * HW_] = (dp[o] + dp[32 * DSTR + o] + dp[2 * 32 * DSTR + o]
                                   + dp[3 * 32 * DSTR + o] + bs[o]) * u;
    }
}

// ---------------------------------------------------------------------------
extern "C" void kernel_launch(void* const* d_in, const int* in_sizes, int n_in,
                              void* d_out, int out_size, void* d_ws, size_t ws_size,
                              hipStream_t stream) {
    const float* input   = (const float*)d_in[0];
    const float* mask_in = (const float*)d_in[1];
    const float* weight  = (const float*)d_in[2];
    const float* bias    = (const float*)d_in[3];
    const float* sem_w   = (const float*)d_in[4];
    const float* sem_b   = (const float*)d_in[5];
    const float* reg_w   = (const float*)d_in[6];
    const float* reg_b   = (const float*)d_in[7];
    const float* m1_w    = (const float*)d_in[8];
    const float* m1_b    = (const float*)d_in[9];
    const float* m2_w    = (const float*)d_in[10];
    const float* m2_b    = (const float*)d_in[11];

    float* out = (float*)d_out;                        // (B,COUT,H,W)
    float* um  = out + (size_t)B_ * COUT * HW_;        // (B,1,H,W)

    short* inpT = (short*)d_ws;                        // B*HW*64
    short* wbm  = inpT + (size_t)B_ * HW_ * 64;        // 36,864
    short* wbs  = wbm + 18 * 4 * 64 * 8;               // 18,432

    prep_kernel<<<NB_NHWC + NB_WT, 256, 0, stream>>>(
        input, weight, sem_w, m2_w, inpT, wbm, wbs);
    fused_kernel<<<B_ * H_ * XT_, 256, 0, stream>>>(
        inpT, mask_in, wbs, wbm, sem_b, reg_w, reg_b, m1_w, m1_b, m2_b,
        bias, out, um);
}